// Round 7
// baseline (886.366 us; speedup 1.0000x reference)
//
#include <hip/hip_runtime.h>
#include <hip/hip_bf16.h>
#include <hip/hip_fp16.h>

// GraphSAGE 2-layer forward. N=100000, E=1.6M, C: 32 -> 64 -> 32.
//
// Round-7: bucket-edge-parallel aggregation with LDS accumulation.
//   partition: (unchanged) edges -> per-bucket packed (ldst<<24|src)
//   agg1: per-bucket LDS accumulate of x rows (fp32 gather) -> aggM, invG
//   dense: per-node fused dense (agg@W1l+b1+x@W1r ->relu-> hW fp16, d2)
//   agg2: per-bucket LDS accumulate of hW rows (fp16 gather) -> out=agg*inv+d2
// bucket_scan / bucket_csr / row_start / sorted_src deleted.

#define BUCKET_SHIFT 8
#define BUCKET_SPAN  256
#define BUCKET_CAP   8192
#define PART_ITEMS   32
#define PART_TILE    (256 * PART_ITEMS)   // 8192 edges

// ---- partition: scatter edges into bucket regions, packed ----
__global__ __launch_bounds__(256) void partition_kernel(
        const int* __restrict__ src, const int* __restrict__ dst,
        int* __restrict__ cursorB, unsigned* __restrict__ edgesB, int E, int nbuck) {
    __shared__ int hist[512];
    __shared__ int rank_[512];
    __shared__ int base[512];
    const int tid = threadIdx.x;
    const int tbase = blockIdx.x * PART_TILE;

    for (int i = tid; i < 512; i += 256) { hist[i] = 0; rank_[i] = 0; }
    __syncthreads();

#pragma unroll
    for (int it = 0; it < PART_ITEMS; ++it) {
        int idx = tbase + it * 256 + tid;
        if (idx < E) atomicAdd(&hist[dst[idx] >> BUCKET_SHIFT], 1);
    }
    __syncthreads();

    for (int i = tid; i < nbuck; i += 256) {
        int h = hist[i];
        base[i] = h ? atomicAdd(&cursorB[i], h) : 0;
    }
    __syncthreads();

#pragma unroll
    for (int it = 0; it < PART_ITEMS; ++it) {
        int idx = tbase + it * 256 + tid;
        if (idx < E) {
            int d = dst[idx];
            int b = d >> BUCKET_SHIFT;
            unsigned ld = (unsigned)(d & (BUCKET_SPAN - 1));
            int r = atomicAdd(&rank_[b], 1);
            edgesB[(size_t)b * BUCKET_CAP + base[b] + r] =
                (ld << 24) | (unsigned)src[idx];
        }
    }
}

// ---- layer-1 aggregation: per-bucket LDS accumulate of x rows ----
__global__ __launch_bounds__(512) void agg1_kernel(
        const float* __restrict__ x, const unsigned* __restrict__ edgesB,
        const int* __restrict__ cursorB,
        float* __restrict__ aggM, float* __restrict__ invG, int N) {
    __shared__ float sAgg[BUCKET_SPAN * 32];   // 32 KB
    __shared__ int sCnt[BUCKET_SPAN];

    const int b = blockIdx.x;
    const int tid = threadIdx.x;
    const int size = cursorB[b];
    const unsigned* eb = edgesB + (size_t)b * BUCKET_CAP;

    for (int i = tid; i < BUCKET_SPAN * 8; i += 512)
        ((float4*)sAgg)[i] = make_float4(0.f, 0.f, 0.f, 0.f);
    if (tid < BUCKET_SPAN) sCnt[tid] = 0;
    __syncthreads();

    const int sub = tid & 7;          // 16B chunk of the 128B row
    const int slot = tid >> 3;        // 0..63 edge slot
    const float4* x4 = (const float4*)x;

    for (int base2 = 0; base2 < size; base2 += 256) {
        unsigned p[4]; bool k[4]; float4 v[4];
#pragma unroll
        for (int u = 0; u < 4; ++u) {
            int i = base2 + u * 64 + slot;
            k[u] = i < size;
            p[u] = k[u] ? eb[i] : 0u;
        }
#pragma unroll
        for (int u = 0; u < 4; ++u)
            v[u] = k[u] ? x4[(size_t)(p[u] & 0xFFFFFFu) * 8 + sub]
                        : make_float4(0.f, 0.f, 0.f, 0.f);
#pragma unroll
        for (int u = 0; u < 4; ++u) {
            if (k[u]) {
                float* ap = sAgg + (p[u] >> 24) * 32 + sub * 4;
                atomicAdd(ap + 0, v[u].x);
                atomicAdd(ap + 1, v[u].y);
                atomicAdd(ap + 2, v[u].z);
                atomicAdd(ap + 3, v[u].w);
                if (sub == 0) atomicAdd(&sCnt[p[u] >> 24], 1);
            }
        }
    }
    __syncthreads();

    const int nodeBase = b << BUCKET_SHIFT;
    const int span = min(BUCKET_SPAN, N - nodeBase);
    for (int u = tid; u < span * 8; u += 512) {
        int node = u >> 3;
        float inv = 1.0f / fmaxf((float)sCnt[node], 1.0f);
        float4 a = ((float4*)sAgg)[u];
        a.x *= inv; a.y *= inv; a.z *= inv; a.w *= inv;
        ((float4*)aggM)[(size_t)nodeBase * 8 + u] = a;
    }
    for (int t = tid; t < span; t += 512)
        invG[nodeBase + t] = 1.0f / fmaxf((float)sCnt[t], 1.0f);
}

// ---- dense (fused): one wave per node, 8 nodes / 512-thread block ----
// h = relu(aggM@W1l + b1 + x@W1r); hW = h@W2l (fp16); d2 = h@W2r + b2
__global__ __launch_bounds__(512) void dense_kernel(
        const float* __restrict__ x, const float* __restrict__ aggM,
        const float* __restrict__ W1l, const float* __restrict__ b1,
        const float* __restrict__ W1r, const float* __restrict__ W2l,
        const float* __restrict__ W2r, const float* __restrict__ b2,
        __half* __restrict__ hWh, float* __restrict__ d2, int N) {
    __shared__ float sW1l[32 * 64];
    __shared__ float sW1r[32 * 64];
    __shared__ float sW2l[64 * 32];
    __shared__ float sW2r[64 * 32];
    __shared__ float sb1[64], sb2[32];
    __shared__ float sAgg[8][32], sX[8][32], sH[8][64];

    {
        int t = threadIdx.x;
        ((float4*)sW1l)[t] = ((const float4*)W1l)[t];
        ((float4*)sW1r)[t] = ((const float4*)W1r)[t];
        ((float4*)sW2l)[t] = ((const float4*)W2l)[t];
        ((float4*)sW2r)[t] = ((const float4*)W2r)[t];
        if (t < 64) sb1[t] = b1[t];
        if (t < 32) sb2[t] = b2[t];
    }
    __syncthreads();

    const int w = threadIdx.x >> 6;
    const int lane = threadIdx.x & 63;
    const int n = blockIdx.x * 8 + w;
    if (n >= N) return;

    if (lane < 8) {
        ((float4*)sAgg[w])[lane] = ((const float4*)aggM)[(size_t)n * 8 + lane];
        ((float4*)sX[w])[lane] = ((const float4*)x)[(size_t)n * 8 + lane];
    }
    // wave-internal LDS exchange (lockstep wave; compiler inserts lgkmcnt)

    float accd = sb1[lane];
#pragma unroll
    for (int k = 0; k < 32; ++k)
        accd += sAgg[w][k] * sW1l[k * 64 + lane] + sX[w][k] * sW1r[k * 64 + lane];
    float hv = fmaxf(accd, 0.0f);
    sH[w][lane] = hv;

    const int c2 = lane & 31;
    const int half = lane >> 5;
    float p1 = 0.f, p2 = 0.f;
#pragma unroll
    for (int kk = 0; kk < 32; ++kk) {
        int k = half * 32 + kk;
        float hk = sH[w][k];
        p1 += hk * sW2l[k * 32 + c2];
        p2 += hk * sW2r[k * 32 + c2];
    }
    p1 += __shfl_xor(p1, 32);
    p2 += __shfl_xor(p2, 32);
    if (lane < 32) {
        hWh[(size_t)n * 32 + c2] = __float2half_rn(p1);
        d2[(size_t)n * 32 + c2] = p2 + sb2[c2];
    }
}

// ---- layer-2 aggregation + epilogue: out = aggLDS(hW)*inv + d2 ----
__global__ __launch_bounds__(512) void agg2_kernel(
        const __half* __restrict__ hWh, const unsigned* __restrict__ edgesB,
        const int* __restrict__ cursorB, const float* __restrict__ invG,
        const float* __restrict__ d2, float* __restrict__ out, int N) {
    __shared__ float sAgg[BUCKET_SPAN * 32];   // 32 KB

    const int b = blockIdx.x;
    const int tid = threadIdx.x;
    const int size = cursorB[b];
    const unsigned* eb = edgesB + (size_t)b * BUCKET_CAP;

    for (int i = tid; i < BUCKET_SPAN * 8; i += 512)
        ((float4*)sAgg)[i] = make_float4(0.f, 0.f, 0.f, 0.f);
    __syncthreads();

    const int sub = tid & 7;          // 8B chunk (4 halves) of the 64B row
    const int slot = tid >> 3;
    const float2* h2 = (const float2*)hWh;

    for (int base2 = 0; base2 < size; base2 += 256) {
        unsigned p[4]; bool k[4]; float2 r[4];
#pragma unroll
        for (int u = 0; u < 4; ++u) {
            int i = base2 + u * 64 + slot;
            k[u] = i < size;
            p[u] = k[u] ? eb[i] : 0u;
        }
#pragma unroll
        for (int u = 0; u < 4; ++u)
            r[u] = k[u] ? h2[(size_t)(p[u] & 0xFFFFFFu) * 8 + sub]
                        : make_float2(0.f, 0.f);
#pragma unroll
        for (int u = 0; u < 4; ++u) {
            if (k[u]) {
                const __half2* hp = (const __half2*)&r[u];
                float2 lo = __half22float2(hp[0]);
                float2 hi = __half22float2(hp[1]);
                float* ap = sAgg + (p[u] >> 24) * 32 + sub * 4;
                atomicAdd(ap + 0, lo.x);
                atomicAdd(ap + 1, lo.y);
                atomicAdd(ap + 2, hi.x);
                atomicAdd(ap + 3, hi.y);
            }
        }
    }
    __syncthreads();

    const int nodeBase = b << BUCKET_SHIFT;
    const int span = min(BUCKET_SPAN, N - nodeBase);
    for (int u = tid; u < span * 8; u += 512) {
        int node = u >> 3;
        float inv = invG[nodeBase + node];
        float4 a = ((float4*)sAgg)[u];
        float4 dd = ((const float4*)d2)[(size_t)nodeBase * 8 + u];
        a.x = a.x * inv + dd.x;
        a.y = a.y * inv + dd.y;
        a.z = a.z * inv + dd.z;
        a.w = a.w * inv + dd.w;
        ((float4*)out)[(size_t)nodeBase * 8 + u] = a;
    }
}

extern "C" void kernel_launch(void* const* d_in, const int* in_sizes, int n_in,
                              void* d_out, int out_size, void* d_ws, size_t ws_size,
                              hipStream_t stream) {
    const float* x   = (const float*)d_in[0];
    const int*   ei  = (const int*)d_in[1];
    const float* W1l = (const float*)d_in[2];
    const float* b1  = (const float*)d_in[3];
    const float* W1r = (const float*)d_in[4];
    const float* W2l = (const float*)d_in[5];
    const float* b2  = (const float*)d_in[6];
    const float* W2r = (const float*)d_in[7];
    float* out = (float*)d_out;

    const int N = in_sizes[0] / 32;    // 100000
    const int E = in_sizes[1] / 2;     // 1600000
    const int* src = ei;
    const int* dst = ei + E;
    const int NBUCK = (N + BUCKET_SPAN - 1) >> BUCKET_SHIFT;   // 391

    char* p = (char*)d_ws;
    auto align64 = [](size_t v) { return (v + 63) & ~(size_t)63; };
    int* cursorB      = (int*)p;      p += align64((size_t)NBUCK * 4);
    unsigned* edgesB  = (unsigned*)p; p += align64((size_t)NBUCK * BUCKET_CAP * 4);
    float* aggM       = (float*)p;    p += align64((size_t)N * 32 * 4);
    float* invG       = (float*)p;    p += align64((size_t)N * 4);
    __half* hWh       = (__half*)p;   p += align64((size_t)N * 32 * 2);
    float* d2         = (float*)p;    p += align64((size_t)N * 32 * 4);

    hipMemsetAsync(cursorB, 0, (size_t)NBUCK * 4, stream);

    int ntiles = (E + PART_TILE - 1) / PART_TILE;   // 196
    partition_kernel<<<ntiles, 256, 0, stream>>>(src, dst, cursorB, edgesB, E, NBUCK);
    agg1_kernel<<<NBUCK, 512, 0, stream>>>(x, edgesB, cursorB, aggM, invG, N);
    dense_kernel<<<(N + 7) / 8, 512, 0, stream>>>(x, aggM, W1l, b1, W1r,
                                                  W2l, W2r, b2, hWh, d2, N);
    agg2_kernel<<<NBUCK, 512, 0, stream>>>(hWh, edgesB, cursorB, invG, d2, out, N);
}

// Round 8
// 265.693 us; speedup vs baseline: 3.3361x; 3.3361x over previous
//
#include <hip/hip_runtime.h>
#include <hip/hip_bf16.h>
#include <hip/hip_fp16.h>

// GraphSAGE 2-layer forward. N=100000, E=1.6M, C: 32 -> 64 -> 32.
//
// Round-8: revert round-7 (LDS-atomic agg was 3x worse: 8-way same-bank
// atomic RMW serialization, 72K bank conflicts, VALU 1.5%). Back to the
// round-6 CSR + per-node wave-gather structure, plus:
//  - x cast to fp16 once (6.4MB table); layer-1 mean-aggregate gathers fp16
//    rows (gather demand 205MB -> 102MB; hypothesis: random-gather is
//    fabric-BW bound at ~1.8TB/s, so bytes are the lever).
//  - self term x[n]@W1r stays fp32 (precision path untouched).

#define BUCKET_SHIFT 8
#define BUCKET_SPAN  256
#define BUCKET_CAP   8192
#define PART_ITEMS   32
#define PART_TILE    (256 * PART_ITEMS)   // 8192 edges

// ---- cast x (fp32) -> xh (fp16), 8 elems/thread ----
__global__ __launch_bounds__(256) void cast_x_kernel(
        const float* __restrict__ x, __half* __restrict__ xh, int total8) {
    int i = blockIdx.x * blockDim.x + threadIdx.x;
    if (i < total8) {
        float4 a = ((const float4*)x)[(size_t)i * 2];
        float4 b = ((const float4*)x)[(size_t)i * 2 + 1];
        struct alignas(16) H8 { __half2 a, b, c, d; } o;
        o.a = __floats2half2_rn(a.x, a.y);
        o.b = __floats2half2_rn(a.z, a.w);
        o.c = __floats2half2_rn(b.x, b.y);
        o.d = __floats2half2_rn(b.z, b.w);
        ((H8*)xh)[i] = o;
    }
}

// ---- partition: scatter edges into bucket regions, packed ----
__global__ __launch_bounds__(256) void partition_kernel(
        const int* __restrict__ src, const int* __restrict__ dst,
        int* __restrict__ cursorB, int* __restrict__ edgesB, int E, int nbuck) {
    __shared__ int hist[512];
    __shared__ int rank_[512];
    __shared__ int base[512];
    const int tid = threadIdx.x;
    const int tbase = blockIdx.x * PART_TILE;

    for (int i = tid; i < 512; i += 256) { hist[i] = 0; rank_[i] = 0; }
    __syncthreads();

#pragma unroll
    for (int it = 0; it < PART_ITEMS; ++it) {
        int idx = tbase + it * 256 + tid;
        if (idx < E) atomicAdd(&hist[dst[idx] >> BUCKET_SHIFT], 1);
    }
    __syncthreads();

    for (int i = tid; i < nbuck; i += 256) {
        int h = hist[i];
        base[i] = h ? atomicAdd(&cursorB[i], h) : 0;
    }
    __syncthreads();

#pragma unroll
    for (int it = 0; it < PART_ITEMS; ++it) {
        int idx = tbase + it * 256 + tid;
        if (idx < E) {
            int d = dst[idx];
            int b = d >> BUCKET_SHIFT;
            int ld = d & (BUCKET_SPAN - 1);
            int r = atomicAdd(&rank_[b], 1);
            edgesB[(size_t)b * BUCKET_CAP + base[b] + r] = (ld << 24) | src[idx];
        }
    }
}

__global__ __launch_bounds__(512) void bucket_scan_kernel(
        const int* __restrict__ cursorB, int* __restrict__ bucketStart, int nbuck) {
    __shared__ int s[512];
    int t = threadIdx.x;
    int v = (t < nbuck) ? cursorB[t] : 0;
    s[t] = v;
    __syncthreads();
    for (int off = 1; off < 512; off <<= 1) {
        int a = (t >= off) ? s[t - off] : 0;
        __syncthreads();
        s[t] += a;
        __syncthreads();
    }
    if (t < nbuck) bucketStart[t] = s[t] - v;
}

__global__ __launch_bounds__(256) void bucket_csr_kernel(
        const int* __restrict__ cursorB, const int* __restrict__ bucketStart,
        const int* __restrict__ edgesB, int* __restrict__ row_start,
        int* __restrict__ sorted_src, int N, int nbuck) {
    __shared__ int cnt[BUCKET_SPAN];
    __shared__ int cur[BUCKET_SPAN];
    __shared__ int sc[BUCKET_SPAN];
    __shared__ int sorted[BUCKET_CAP];

    const int b = blockIdx.x;
    const int t = threadIdx.x;
    const int nodeBase = b << BUCKET_SHIFT;
    const int span = min(BUCKET_SPAN, N - nodeBase);
    const int size = cursorB[b];
    const int gstart = bucketStart[b];
    const int* eb = edgesB + (size_t)b * BUCKET_CAP;

    cnt[t] = 0;
    __syncthreads();
    for (int i = t; i < size; i += 256) atomicAdd(&cnt[((unsigned)eb[i]) >> 24], 1);
    __syncthreads();

    sc[t] = cnt[t];
    __syncthreads();
    for (int off = 1; off < BUCKET_SPAN; off <<= 1) {
        int a = (t >= off) ? sc[t - off] : 0;
        __syncthreads();
        sc[t] += a;
        __syncthreads();
    }
    int excl = sc[t] - cnt[t];
    if (t < span) row_start[nodeBase + t] = gstart + excl;
    if (b == nbuck - 1 && t == 0) row_start[N] = gstart + size;
    cur[t] = excl;
    __syncthreads();

    for (int i = t; i < size; i += 256) {
        int p = eb[i];
        int r = atomicAdd(&cur[((unsigned)p) >> 24], 1);
        sorted[r] = p & 0xFFFFFF;
    }
    __syncthreads();
    for (int i = t; i < size; i += 256) sorted_src[gstart + i] = sorted[i];
}

// ---- wave-cooperative gather-sum, fp16 rows (32ch = 8 float2 units) ----
// One coalesced index load covers 64 edges; up to 8 row-gathers issued
// back-to-back; indices broadcast via __shfl (no memory dependence chain).
__device__ __forceinline__ float4 gather_sum_f16(const float2* __restrict__ t2,
                                                 const int* __restrict__ sp,
                                                 int deg, int lane) {
    const int sub = lane & 7;
    const int rowi = lane >> 3;
    float4 acc = make_float4(0.f, 0.f, 0.f, 0.f);
    for (int base = 0; base < deg; base += 64) {
        int chunk = min(deg - base, 64);
        int myidx = (lane < chunk) ? sp[base + lane] : -1;
        int nit = (chunk + 7) >> 3;
        int e[8];
        float2 v[8];
#pragma unroll
        for (int it = 0; it < 8; ++it)
            e[it] = (it < nit) ? __shfl(myidx, it * 8 + rowi) : -1;
#pragma unroll
        for (int it = 0; it < 8; ++it)
            v[it] = (e[it] >= 0) ? t2[(size_t)e[it] * 8 + sub]
                                 : make_float2(0.f, 0.f);
#pragma unroll
        for (int it = 0; it < 8; ++it) {
            const __half2* hp = (const __half2*)&v[it];
            float2 lo = __half22float2(hp[0]);
            float2 hi = __half22float2(hp[1]);
            acc.x += lo.x; acc.y += lo.y; acc.z += hi.x; acc.w += hi.y;
        }
    }
#pragma unroll
    for (int off = 8; off < 64; off <<= 1) {
        acc.x += __shfl_xor(acc.x, off);
        acc.y += __shfl_xor(acc.y, off);
        acc.z += __shfl_xor(acc.z, off);
        acc.w += __shfl_xor(acc.w, off);
    }
    return acc;
}

// ---- layer1 (fused): one wave per node, 8 nodes / 512-thread block ----
// agg = mean-gather xh[src] (fp16); h = relu(agg@W1l + b1 + x@W1r) (x fp32);
// hW = h@W2l (fp16 out); d2 = h@W2r + b2.
__global__ __launch_bounds__(512) void layer1_kernel(
        const float* __restrict__ x, const __half* __restrict__ xh,
        const int* __restrict__ row_start, const int* __restrict__ sorted_src,
        const float* __restrict__ W1l, const float* __restrict__ b1,
        const float* __restrict__ W1r, const float* __restrict__ W2l,
        const float* __restrict__ W2r, const float* __restrict__ b2,
        __half* __restrict__ hWh, float* __restrict__ d2, int N) {
    __shared__ float sW1l[32 * 64];
    __shared__ float sW1r[32 * 64];
    __shared__ float sW2l[64 * 32];
    __shared__ float sW2r[64 * 32];
    __shared__ float sb1[64], sb2[32];
    __shared__ float sAgg[8][32], sX[8][32], sH[8][64];

    {
        int t = threadIdx.x;
        ((float4*)sW1l)[t] = ((const float4*)W1l)[t];
        ((float4*)sW1r)[t] = ((const float4*)W1r)[t];
        ((float4*)sW2l)[t] = ((const float4*)W2l)[t];
        ((float4*)sW2r)[t] = ((const float4*)W2r)[t];
        if (t < 64) sb1[t] = b1[t];
        if (t < 32) sb2[t] = b2[t];
    }
    __syncthreads();

    const int w = threadIdx.x >> 6;
    const int lane = threadIdx.x & 63;
    const int n = blockIdx.x * 8 + w;
    if (n >= N) return;

    int rs = row_start[n];
    int re = row_start[n + 1];
    int deg = re - rs;
    float inv = 1.0f / fmaxf((float)deg, 1.0f);
    const float4* x4 = (const float4*)x;

    float4 acc = gather_sum_f16((const float2*)xh, sorted_src + rs, deg, lane);

    if (lane < 8) {
        float4 m;
        m.x = acc.x * inv; m.y = acc.y * inv; m.z = acc.z * inv; m.w = acc.w * inv;
        ((float4*)sAgg[w])[lane] = m;
        ((float4*)sX[w])[lane] = x4[(size_t)n * 8 + lane];
    }
    // wave-internal LDS exchange (lockstep wave; compiler inserts lgkmcnt)

    float accd = sb1[lane];
#pragma unroll
    for (int k = 0; k < 32; ++k)
        accd += sAgg[w][k] * sW1l[k * 64 + lane] + sX[w][k] * sW1r[k * 64 + lane];
    float hv = fmaxf(accd, 0.0f);
    sH[w][lane] = hv;

    const int c2 = lane & 31;
    const int half = lane >> 5;
    float p1 = 0.f, p2 = 0.f;
#pragma unroll
    for (int kk = 0; kk < 32; ++kk) {
        int k = half * 32 + kk;
        float hk = sH[w][k];
        p1 += hk * sW2l[k * 32 + c2];
        p2 += hk * sW2r[k * 32 + c2];
    }
    p1 += __shfl_xor(p1, 32);
    p2 += __shfl_xor(p2, 32);
    if (lane < 32) {
        hWh[(size_t)n * 32 + c2] = __float2half_rn(p1);
        d2[(size_t)n * 32 + c2] = p2 + sb2[c2];
    }
}

// ---- layer2: out = gather-mean(hW[src], fp16) + d2 ----
__global__ __launch_bounds__(256) void layer2_kernel(
        const __half* __restrict__ hWh, const float* __restrict__ d2,
        const int* __restrict__ row_start, const int* __restrict__ sorted_src,
        float* __restrict__ out, int N) {
    const int w = threadIdx.x >> 6;
    const int lane = threadIdx.x & 63;
    const int n = blockIdx.x * 4 + w;
    if (n >= N) return;

    int rs = row_start[n];
    int re = row_start[n + 1];
    int deg = re - rs;
    float inv = 1.0f / fmaxf((float)deg, 1.0f);

    float4 acc = gather_sum_f16((const float2*)hWh, sorted_src + rs, deg, lane);

    if (lane < 8) {
        float4 dd = ((const float4*)d2)[(size_t)n * 8 + lane];
        float4 o;
        o.x = acc.x * inv + dd.x;
        o.y = acc.y * inv + dd.y;
        o.z = acc.z * inv + dd.z;
        o.w = acc.w * inv + dd.w;
        ((float4*)out)[(size_t)n * 8 + lane] = o;
    }
}

extern "C" void kernel_launch(void* const* d_in, const int* in_sizes, int n_in,
                              void* d_out, int out_size, void* d_ws, size_t ws_size,
                              hipStream_t stream) {
    const float* x   = (const float*)d_in[0];
    const int*   ei  = (const int*)d_in[1];
    const float* W1l = (const float*)d_in[2];
    const float* b1  = (const float*)d_in[3];
    const float* W1r = (const float*)d_in[4];
    const float* W2l = (const float*)d_in[5];
    const float* b2  = (const float*)d_in[6];
    const float* W2r = (const float*)d_in[7];
    float* out = (float*)d_out;

    const int N = in_sizes[0] / 32;    // 100000
    const int E = in_sizes[1] / 2;     // 1600000
    const int* src = ei;
    const int* dst = ei + E;
    const int NBUCK = (N + BUCKET_SPAN - 1) >> BUCKET_SHIFT;   // 391

    char* p = (char*)d_ws;
    auto align64 = [](size_t v) { return (v + 63) & ~(size_t)63; };
    int* cursorB     = (int*)p;    p += align64((size_t)NBUCK * 4);
    int* bucketStart = (int*)p;    p += align64((size_t)(NBUCK + 1) * 4);
    int* row_start   = (int*)p;    p += align64((size_t)(N + 1) * 4);
    int* sorted_src  = (int*)p;    p += align64((size_t)E * 4);
    int* edgesB      = (int*)p;    p += align64((size_t)NBUCK * BUCKET_CAP * 4);
    __half* xh       = (__half*)p; p += align64((size_t)N * 32 * 2);
    __half* hWh      = (__half*)p; p += align64((size_t)N * 32 * 2);
    float* d2        = (float*)p;  p += align64((size_t)N * 32 * 4);

    hipMemsetAsync(cursorB, 0, (size_t)NBUCK * 4, stream);

    int total8 = N * 4;   // N*32 elems / 8 per thread
    cast_x_kernel<<<(total8 + 255) / 256, 256, 0, stream>>>(x, xh, total8);

    int ntiles = (E + PART_TILE - 1) / PART_TILE;   // 196
    partition_kernel<<<ntiles, 256, 0, stream>>>(src, dst, cursorB, edgesB, E, NBUCK);
    bucket_scan_kernel<<<1, 512, 0, stream>>>(cursorB, bucketStart, NBUCK);
    bucket_csr_kernel<<<NBUCK, 256, 0, stream>>>(cursorB, bucketStart, edgesB,
                                                 row_start, sorted_src, N, NBUCK);

    layer1_kernel<<<(N + 7) / 8, 512, 0, stream>>>(x, xh, row_start, sorted_src,
                                                   W1l, b1, W1r, W2l, W2r, b2,
                                                   hWh, d2, N);
    layer2_kernel<<<(N + 3) / 4, 256, 0, stream>>>(hWh, d2, row_start, sorted_src,
                                                   out, N);
}